// Round 1
// baseline (460.842 us; speedup 1.0000x reference)
//
#include <hip/hip_runtime.h>

#define BATCH   8192
#define CLASSES 10000
#define NV4     2500        // CLASSES / 4
#define TPB     256
#define MAIN_BLOCKS 512     // 16 rows per block

// ---------------- zero workspace ----------------
__global__ void zero_ws_kernel(float* __restrict__ conf, int* __restrict__ counts) {
    int i = blockIdx.x * blockDim.x + threadIdx.x;
    if (i < CLASSES) { conf[i] = 0.0f; counts[i] = 0; }
}

// ---------------- label histogram ----------------
__global__ void hist_kernel(const int* __restrict__ target, int* __restrict__ counts) {
    int i = blockIdx.x * blockDim.x + threadIdx.x;
    if (i < BATCH) atomicAdd(&counts[target[i]], 1);
}

// ---------------- per-row softmax + per-class accumulation ----------------
__global__ __launch_bounds__(TPB) void conf_kernel(const float* __restrict__ out,
                                                   float* __restrict__ conf) {
    __shared__ float acc[CLASSES];     // 40000 B
    __shared__ float redm[4];
    __shared__ float reds[4];

    const int tid  = threadIdx.x;
    const int lane = tid & 63;
    const int wave = tid >> 6;

    // zero LDS accumulator (float4 stores)
    for (int i = tid; i < NV4; i += TPB)
        ((float4*)acc)[i] = make_float4(0.f, 0.f, 0.f, 0.f);
    __syncthreads();

    const int nfull = NV4 / TPB;          // 9 full float4 chunks per thread
    const int rem   = NV4 - nfull * TPB;  // 196
    const int myv   = nfull + (tid < rem ? 1 : 0);   // 9 or 10

    for (int r = blockIdx.x; r < BATCH; r += gridDim.x) {
        const float4* row = (const float4*)(out + (size_t)r * CLASSES);

        float4 v[10];
        float  m = -3.4e38f;
        #pragma unroll
        for (int k = 0; k < 10; ++k) {
            if (k < myv) {
                v[k] = row[tid + k * TPB];
                m = fmaxf(m, fmaxf(fmaxf(v[k].x, v[k].y), fmaxf(v[k].z, v[k].w)));
            }
        }

        // block-reduce max (wave shfl + cross-wave LDS)
        #pragma unroll
        for (int off = 32; off > 0; off >>= 1)
            m = fmaxf(m, __shfl_xor(m, off, 64));
        if (lane == 0) redm[wave] = m;
        __syncthreads();                                   // barrier 1
        m = fmaxf(fmaxf(redm[0], redm[1]), fmaxf(redm[2], redm[3]));

        // exp(x - m) in place, local sum
        float s = 0.f;
        #pragma unroll
        for (int k = 0; k < 10; ++k) {
            if (k < myv) {
                v[k].x = __expf(v[k].x - m);
                v[k].y = __expf(v[k].y - m);
                v[k].z = __expf(v[k].z - m);
                v[k].w = __expf(v[k].w - m);
                s += v[k].x + v[k].y + v[k].z + v[k].w;
            }
        }
        #pragma unroll
        for (int off = 32; off > 0; off >>= 1)
            s += __shfl_xor(s, off, 64);
        if (lane == 0) reds[wave] = s;
        __syncthreads();                                   // barrier 2
        s = reds[0] + reds[1] + reds[2] + reds[3];
        const float inv = 1.0f / s;

        // accumulate p = e * inv into per-block LDS accumulator.
        // thread t exclusively owns acc[(t + k*TPB)*4 .. +3] -> race-free RMW,
        // lane i at 16B address base+16i -> conflict-free ds_read/write_b128.
        #pragma unroll
        for (int k = 0; k < 10; ++k) {
            if (k < myv) {
                float4* a = (float4*)&acc[(tid + k * TPB) * 4];
                float4 av = *a;
                av.x += v[k].x * inv;
                av.y += v[k].y * inv;
                av.z += v[k].z * inv;
                av.w += v[k].w * inv;
                *a = av;
            }
        }
        // no extra barrier needed: redm/reds WAR hazards are covered by
        // barriers 1/2 of the next iteration (reads happen before those).
    }

    __syncthreads();
    // flush per-block accumulator to global (5.12M atomics total over 10000 addrs)
    for (int i = tid; i < CLASSES; i += TPB)
        atomicAdd(&conf[i], acc[i]);
}

// ---------------- final loss reduction ----------------
__global__ void loss_kernel(const float* __restrict__ conf,
                            const int* __restrict__ counts,
                            float* __restrict__ out) {
    __shared__ float red[4];
    const int tid  = threadIdx.x;
    const int lane = tid & 63;
    const int wave = tid >> 6;

    float local = 0.f;
    for (int c = tid; c < CLASSES; c += TPB)
        local += fabsf(conf[c] - (float)counts[c]);

    #pragma unroll
    for (int off = 32; off > 0; off >>= 1)
        local += __shfl_xor(local, off, 64);
    if (lane == 0) red[wave] = local;
    __syncthreads();
    if (tid == 0) {
        float t = red[0] + red[1] + red[2] + red[3];
        out[0] = t * (1.0f / (float)BATCH) * (1.0f / (float)CLASSES);
    }
}

extern "C" void kernel_launch(void* const* d_in, const int* in_sizes, int n_in,
                              void* d_out, int out_size, void* d_ws, size_t ws_size,
                              hipStream_t stream) {
    const float* output = (const float*)d_in[0];
    const int*   target = (const int*)d_in[1];
    float*       outp   = (float*)d_out;

    // workspace layout: conf[10000] f32 @0, counts[10000] i32 @40960
    float* conf   = (float*)d_ws;
    int*   counts = (int*)((char*)d_ws + 40960);

    zero_ws_kernel<<<(CLASSES + TPB - 1) / TPB, TPB, 0, stream>>>(conf, counts);
    hist_kernel<<<(BATCH + TPB - 1) / TPB, TPB, 0, stream>>>(target, counts);
    conf_kernel<<<MAIN_BLOCKS, TPB, 0, stream>>>(output, conf);
    loss_kernel<<<1, TPB, 0, stream>>>(conf, counts, outp);
}